// Round 1
// baseline (448.391 us; speedup 1.0000x reference)
//
#include <hip/hip_runtime.h>
#include <stdint.h>

// Problem constants: B=2, T=2048, D_MODEL=1536, H=16, hd=96, n_trip=32.
// qkv row length = 3*1536 = 4608, rows = B*T = 4096.

typedef unsigned short u16;
typedef unsigned int u32;
typedef __attribute__((ext_vector_type(8))) __bf16 bf16x8;   // MFMA A/B frag (4 VGPRs)
typedef __attribute__((ext_vector_type(4))) float f32x4;     // MFMA C/D frag

#define DEV static __device__ __forceinline__

DEV u16 f2bf(float f) {
  u32 u = __float_as_uint(f);
  u32 r = (u + 0x7fffu + ((u >> 16) & 1u)) >> 16;  // round-nearest-even
  return (u16)r;
}
DEV float bf2f(u16 h) { return __uint_as_float(((u32)h) << 16); }

// async global->LDS, 16B per lane. LDS dest is wave-uniform base + lane*16.
DEV void gload16(u16* lds_dst, const u16* gsrc) {
  __builtin_amdgcn_global_load_lds(
      (const __attribute__((address_space(1))) void*)gsrc,
      (__attribute__((address_space(3))) void*)lds_dst, 16, 0, 0);
}

// ---------------------------------------------------------------- cvt f32->bf16
__global__ __launch_bounds__(256) void cvt_bf16(const float* __restrict__ in,
                                                u16* __restrict__ out, int n4) {
  int i = blockIdx.x * 256 + threadIdx.x;
  if (i < n4) {
    float4 v = reinterpret_cast<const float4*>(in)[i];
    ushort4 o;
    o.x = f2bf(v.x); o.y = f2bf(v.y); o.z = f2bf(v.z); o.w = f2bf(v.w);
    reinterpret_cast<ushort4*>(out)[i] = o;
  }
}

// ---------------------------------------------------------------- GEMM C = A * B^T
// A: [M][K] bf16 row-major, B: [N][K] bf16 row-major ("B^T input").
// m97 structure: 128x128 tile, BK=32, 4 waves (2x2 of 64x64), global_load_lds x16.
template <int OUT_BF16>
__global__ __launch_bounds__(256) void gemm_bt(const u16* __restrict__ A,
                                               const u16* __restrict__ B,
                                               void* __restrict__ Cv,
                                               int M, int N, int K) {
  __shared__ __align__(16) u16 lA[128 * 32];
  __shared__ __align__(16) u16 lB[128 * 32];
  const int tid = threadIdx.x;
  const int lane = tid & 63;
  const int w = tid >> 6;
  const int wr = (w >> 1) * 64;   // wave row offset in tile
  const int wc = (w & 1) * 64;    // wave col offset in tile
  const int fr = lane & 15;       // fragment row (A/B: m/n = lane&15)
  const int fq = lane >> 4;       // quarter: k-offset = fq*8
  const int row0 = blockIdx.x * 128;
  const int col0 = blockIdx.y * 128;

  const f32x4 z4 = {0.f, 0.f, 0.f, 0.f};
  f32x4 acc[4][4];
#pragma unroll
  for (int m = 0; m < 4; ++m)
#pragma unroll
    for (int n = 0; n < 4; ++n) acc[m][n] = z4;

  const int sr = tid >> 2;        // staging row within 64-row group
  const int sc = (tid & 3) * 8;   // staging col (8 bf16 = 16B)

  for (int k0 = 0; k0 < K; k0 += 32) {
    __syncthreads();  // previous iteration's LDS reads done
#pragma unroll
    for (int rep = 0; rep < 2; ++rep) {
      const int row = rep * 64 + sr;
      const int ldsbase = (rep * 256 + w * 64) * 8;  // elements; wave-uniform
      gload16(lA + ldsbase, A + (size_t)(row0 + row) * K + (k0 + sc));
      gload16(lB + ldsbase, B + (size_t)(col0 + row) * K + (k0 + sc));
    }
    __syncthreads();  // staging complete (vmcnt drained by barrier)

    bf16x8 af[4], bfr[4];
#pragma unroll
    for (int m = 0; m < 4; ++m)
      af[m] = *reinterpret_cast<const bf16x8*>(lA + (wr + m * 16 + fr) * 32 + fq * 8);
#pragma unroll
    for (int n = 0; n < 4; ++n)
      bfr[n] = *reinterpret_cast<const bf16x8*>(lB + (wc + n * 16 + fr) * 32 + fq * 8);
#pragma unroll
    for (int m = 0; m < 4; ++m)
#pragma unroll
      for (int n = 0; n < 4; ++n)
        acc[m][n] = __builtin_amdgcn_mfma_f32_16x16x32_bf16(af[m], bfr[n], acc[m][n], 0, 0, 0);
  }

  // C/D layout: col = lane&15, row = (lane>>4)*4 + reg
#pragma unroll
  for (int m = 0; m < 4; ++m) {
    const int grow0 = row0 + wr + m * 16 + fq * 4;
#pragma unroll
    for (int n = 0; n < 4; ++n) {
      const int gcol = col0 + wc + n * 16 + fr;
#pragma unroll
      for (int j = 0; j < 4; ++j) {
        const size_t off = (size_t)(grow0 + j) * N + gcol;
        if (OUT_BF16) ((u16*)Cv)[off] = f2bf(acc[m][n][j]);
        else          ((float*)Cv)[off] = acc[m][n][j];
      }
    }
  }
}

// ---------------------------------------------------------------- 3D RoPE on q,k
// One block per (bt, qk): rotates 16 heads x 32 triplets of 3 elems, in place.
__global__ __launch_bounds__(256) void rope_kernel(u16* __restrict__ qkv,
                                                   const float* __restrict__ Rs) {
  const int bid = blockIdx.x;        // [0, 8192)
  const int qk = bid & 1;            // 0 = q part, 1 = k part
  const int bt = bid >> 1;           // [0, 4096)
  const int t = bt & 2047;
  const int tid = threadIdx.x;

  __shared__ __align__(16) u16 buf[1536];
  __shared__ __align__(16) float rbuf[288];  // Rs[t]: 32 triplets x 3 x 3

  u16* g = qkv + (size_t)bt * 4608 + qk * 1536;
  if (tid < 192)
    *reinterpret_cast<uint4*>(buf + tid * 8) = *reinterpret_cast<const uint4*>(g + tid * 8);
  if (tid < 72)
    *reinterpret_cast<float4*>(rbuf + tid * 4) =
        *reinterpret_cast<const float4*>(Rs + (size_t)t * 288 + tid * 4);
  __syncthreads();

#pragma unroll
  for (int rep = 0; rep < 2; ++rep) {
    const int ft = rep * 256 + tid;  // triplet id in [0,512): h = ft>>5, trip = ft&31
    const int base = (ft >> 5) * 96 + (ft & 31) * 3;
    const float* R = rbuf + (ft & 31) * 9;
    const float x0 = bf2f(buf[base]), x1 = bf2f(buf[base + 1]), x2 = bf2f(buf[base + 2]);
    const float y0 = R[0] * x0 + R[1] * x1 + R[2] * x2;
    const float y1 = R[3] * x0 + R[4] * x1 + R[5] * x2;
    const float y2 = R[6] * x0 + R[7] * x1 + R[8] * x2;
    buf[base] = f2bf(y0); buf[base + 1] = f2bf(y1); buf[base + 2] = f2bf(y2);
  }
  __syncthreads();
  if (tid < 192)
    *reinterpret_cast<uint4*>(g + tid * 8) = *reinterpret_cast<const uint4*>(buf + tid * 8);
}

// ---------------------------------------------------------------- flash attention
// Block = (64 Q-rows, one bh). 4 waves x 16 rows. KV tiles of 64. Causal.
__global__ __launch_bounds__(256) void attn_fwd(const u16* __restrict__ qkv,
                                                u16* __restrict__ y) {
  const int qt = blockIdx.x;
  const int bh = blockIdx.y;
  const int b = bh >> 4, h = bh & 15;
  const int q0 = qt * 64;
  const int tid = threadIdx.x;
  const int lane = tid & 63;
  const int w = tid >> 6;
  const int fr = lane & 15;
  const int fq = lane >> 4;

  __shared__ __align__(16) u16 k_lds[64 * 96];     // [kv][d] linear (gload_lds)
  __shared__ __align__(16) u16 vt_lds[96 * 80];    // [d][kv], rows padded to 80
  __shared__ __align__(16) u16 p_lds[4][16 * 72];  // per-wave P, rows padded to 72

  // Q fragments in registers: wave w owns rows q0+w*16 .. +15
  const size_t qrow = (size_t)(b * 2048 + q0 + w * 16 + fr) * 4608;
  bf16x8 qf[3];
#pragma unroll
  for (int kb = 0; kb < 3; ++kb)
    qf[kb] = *reinterpret_cast<const bf16x8*>(qkv + qrow + h * 96 + kb * 32 + fq * 8);

  const f32x4 z4 = {0.f, 0.f, 0.f, 0.f};
  f32x4 oacc[6];
#pragma unroll
  for (int n = 0; n < 6; ++n) oacc[n] = z4;
  float mrow[4], ssum[4];
#pragma unroll
  for (int j = 0; j < 4; ++j) { mrow[j] = -1e30f; ssum[j] = 0.f; }

  const int nt = qt + 1;                          // causal: tiles k0 = 0..q0
  const float scale = 0.1020620726159657f;        // 1/sqrt(96)
  const int wave_qmax = q0 + w * 16 + 15;

  for (int kt = 0; kt < nt; ++kt) {
    const int k0 = kt * 64;
    // ---- stage K [64][96] linear via global_load_lds
#pragma unroll
    for (int rep = 0; rep < 3; ++rep) {
      const int idx = rep * 256 + tid;            // [0,768)
      const int kv = idx / 12;
      const int c8 = (idx % 12) * 8;
      gload16(k_lds + (rep * 256 + w * 64) * 8,
              qkv + (size_t)(b * 2048 + k0 + kv) * 4608 + 1536 + h * 96 + c8);
    }
    // ---- stage V transposed [d][kv] with lane-rotated writes (bank spread)
#pragma unroll
    for (int rep = 0; rep < 3; ++rep) {
      const int idx = rep * 256 + tid;
      const int kv = idx / 12;
      const int d0 = (idx % 12) * 8;
      const uint4 vv = *reinterpret_cast<const uint4*>(
          qkv + (size_t)(b * 2048 + k0 + kv) * 4608 + 3072 + h * 96 + d0);
#pragma unroll
      for (int jj = 0; jj < 8; ++jj) {
        const int i = (jj + lane) & 7;
        const u32 word = (i & 4) ? ((i & 2) ? vv.w : vv.z) : ((i & 2) ? vv.y : vv.x);
        vt_lds[(d0 + i) * 80 + kv] = (u16)(word >> ((i & 1) * 16));
      }
    }
    __syncthreads();

    if (k0 <= wave_qmax) {  // wave has at least one unmasked element in this tile
      // ---- S = Q K^T : 16x64, acc rows = (fq*4+j), cols = nb*16+fr
      f32x4 sacc[4];
#pragma unroll
      for (int n = 0; n < 4; ++n) sacc[n] = z4;
#pragma unroll
      for (int kb = 0; kb < 3; ++kb) {
#pragma unroll
        for (int n = 0; n < 4; ++n) {
          const bf16x8 kf = *reinterpret_cast<const bf16x8*>(
              k_lds + (n * 16 + fr) * 96 + kb * 32 + fq * 8);
          sacc[n] = __builtin_amdgcn_mfma_f32_16x16x32_bf16(qf[kb], kf, sacc[n], 0, 0, 0);
        }
      }
      float sv[4][4];
#pragma unroll
      for (int n = 0; n < 4; ++n)
#pragma unroll
        for (int j = 0; j < 4; ++j) sv[n][j] = sacc[n][j] * scale;
      if (kt == nt - 1) {  // diagonal tile: mask kvpos > qpos
#pragma unroll
        for (int n = 0; n < 4; ++n) {
          const int kvpos = k0 + n * 16 + fr;
#pragma unroll
          for (int j = 0; j < 4; ++j) {
            const int qpos = q0 + w * 16 + fq * 4 + j;
            if (kvpos > qpos) sv[n][j] = -1e30f;
          }
        }
      }
      // ---- online softmax (rows live in 16-lane groups: shfl_xor 1/2/4/8)
      float mx[4];
#pragma unroll
      for (int j = 0; j < 4; ++j)
        mx[j] = fmaxf(fmaxf(sv[0][j], sv[1][j]), fmaxf(sv[2][j], sv[3][j]));
#pragma unroll
      for (int off = 1; off < 16; off <<= 1)
#pragma unroll
        for (int j = 0; j < 4; ++j) mx[j] = fmaxf(mx[j], __shfl_xor(mx[j], off));
      float al[4];
#pragma unroll
      for (int j = 0; j < 4; ++j) {
        const float mn = fmaxf(mrow[j], mx[j]);
        al[j] = __expf(mrow[j] - mn);
        mrow[j] = mn;
      }
      float pvv[4][4];
#pragma unroll
      for (int n = 0; n < 4; ++n)
#pragma unroll
        for (int j = 0; j < 4; ++j) pvv[n][j] = __expf(sv[n][j] - mrow[j]);
      float rs[4];
#pragma unroll
      for (int j = 0; j < 4; ++j)
        rs[j] = (pvv[0][j] + pvv[1][j]) + (pvv[2][j] + pvv[3][j]);
#pragma unroll
      for (int off = 1; off < 16; off <<= 1)
#pragma unroll
        for (int j = 0; j < 4; ++j) rs[j] += __shfl_xor(rs[j], off);
#pragma unroll
      for (int j = 0; j < 4; ++j) ssum[j] = ssum[j] * al[j] + rs[j];
#pragma unroll
      for (int n = 0; n < 6; ++n) {
        f32x4 t = oacc[n];
        t[0] *= al[0]; t[1] *= al[1]; t[2] *= al[2]; t[3] *= al[3];
        oacc[n] = t;
      }
      // ---- P -> per-wave LDS (C-layout write), reread as A-frag
#pragma unroll
      for (int n = 0; n < 4; ++n)
#pragma unroll
        for (int j = 0; j < 4; ++j)
          p_lds[w][(fq * 4 + j) * 72 + n * 16 + fr] = f2bf(pvv[n][j]);
      // ---- O += P V
#pragma unroll
      for (int kb2 = 0; kb2 < 2; ++kb2) {
        const bf16x8 pa = *reinterpret_cast<const bf16x8*>(
            &p_lds[w][fr * 72 + kb2 * 32 + fq * 8]);
#pragma unroll
        for (int n2 = 0; n2 < 6; ++n2) {
          const bf16x8 vb = *reinterpret_cast<const bf16x8*>(
              vt_lds + (n2 * 16 + fr) * 80 + kb2 * 32 + fq * 8);
          oacc[n2] = __builtin_amdgcn_mfma_f32_16x16x32_bf16(pa, vb, oacc[n2], 0, 0, 0);
        }
      }
    }
    __syncthreads();  // protect k_lds / vt_lds before next staging
  }

  // ---- epilogue: y[bt][h*96 + d] = O / ssum  (bf16)
  float inv[4];
#pragma unroll
  for (int j = 0; j < 4; ++j) inv[j] = 1.0f / ssum[j];
#pragma unroll
  for (int n2 = 0; n2 < 6; ++n2)
#pragma unroll
    for (int j = 0; j < 4; ++j) {
      const size_t off =
          (size_t)(b * 2048 + q0 + w * 16 + fq * 4 + j) * 1536 + h * 96 + n2 * 16 + fr;
      y[off] = f2bf(oacc[n2][j] * inv[j]);
    }
}

// ---------------------------------------------------------------- launch
extern "C" void kernel_launch(void* const* d_in, const int* in_sizes, int n_in,
                              void* d_out, int out_size, void* d_ws, size_t ws_size,
                              hipStream_t stream) {
  (void)in_sizes; (void)n_in; (void)out_size; (void)ws_size;
  const float* x     = (const float*)d_in[0];   // (2,2048,1536)
  const float* w_qkv = (const float*)d_in[1];   // (4608,1536)
  const float* w_o   = (const float*)d_in[2];   // (1536,1536)
  const float* Rs    = (const float*)d_in[3];   // (4096,32,3,3)
  float* out = (float*)d_out;                   // (2,2048,1536) f32

  // ws layout (bf16 elements):
  u16* xb    = (u16*)d_ws;          // 6291456
  u16* wqkvb = xb + 6291456;        // 7077888
  u16* wob   = wqkvb + 7077888;     // 2359296
  u16* qkvb  = wob + 2359296;       // 4096*4608 = 18874368
  u16* yb    = qkvb + 18874368;     // 6291456   (total ~81.8 MB)

  cvt_bf16<<<1572864 / 256, 256, 0, stream>>>(x, xb, 1572864);
  cvt_bf16<<<1769472 / 256, 256, 0, stream>>>(w_qkv, wqkvb, 1769472);
  cvt_bf16<<<589824 / 256, 256, 0, stream>>>(w_o, wob, 589824);

  gemm_bt<1><<<dim3(32, 36), 256, 0, stream>>>(xb, wqkvb, (void*)qkvb, 4096, 4608, 1536);
  rope_kernel<<<8192, 256, 0, stream>>>(qkvb, Rs);
  attn_fwd<<<dim3(32, 32), 256, 0, stream>>>(qkvb, yb);
  gemm_bt<0><<<dim3(32, 12), 256, 0, stream>>>(yb, wob, (void*)out, 4096, 1536, 1536);
}

// Round 2
// 328.235 us; speedup vs baseline: 1.3661x; 1.3661x over previous
//
#include <hip/hip_runtime.h>
#include <stdint.h>

// B=2, T=2048, D_MODEL=1536, H=16, hd=96, n_trip=32. qkv row = 4608, rows = 4096.

typedef unsigned short u16;
typedef unsigned int u32;
typedef __attribute__((ext_vector_type(8))) __bf16 bf16x8;   // MFMA A/B frag
typedef __attribute__((ext_vector_type(4))) float f32x4;     // MFMA C/D frag

#define DEV static __device__ __forceinline__

DEV u16 f2bf(float f) {
  u32 u = __float_as_uint(f);
  return (u16)((u + 0x7fffu + ((u >> 16) & 1u)) >> 16);  // RNE
}
DEV float bf2f(u16 h) { return __uint_as_float(((u32)h) << 16); }
DEV u32 cvtpk(float lo, float hi) {  // packed f32->bf16 pair (lo->bits[15:0])
  u32 r;
  asm("v_cvt_pk_bf16_f32 %0, %1, %2" : "=v"(r) : "v"(lo), "v"(hi));
  return r;
}
DEV float exp2f_fast(float x) {
  float r;
  asm("v_exp_f32 %0, %1" : "=v"(r) : "v"(x));
  return r;
}

// async global->LDS, 16B/lane. LDS dest = wave-uniform base + lane*16.
DEV void gload16(u16* lds_dst, const u16* gsrc) {
  __builtin_amdgcn_global_load_lds(
      (const __attribute__((address_space(1))) void*)gsrc,
      (__attribute__((address_space(3))) void*)lds_dst, 16, 0, 0);
}

// ---------------------------------------------------------------- cvt f32->bf16
__global__ __launch_bounds__(256) void cvt_bf16(const float* __restrict__ in,
                                                u16* __restrict__ out, int n4) {
  int i = blockIdx.x * 256 + threadIdx.x;
  if (i < n4) {
    float4 v = reinterpret_cast<const float4*>(in)[i];
    ushort4 o;
    o.x = f2bf(v.x); o.y = f2bf(v.y); o.z = f2bf(v.z); o.w = f2bf(v.w);
    reinterpret_cast<ushort4*>(out)[i] = o;
  }
}

// ---------------------------------------------------------------- GEMM C = A * B^T
template <int OUT_BF16>
__global__ __launch_bounds__(256) void gemm_bt(const u16* __restrict__ A,
                                               const u16* __restrict__ B,
                                               void* __restrict__ Cv,
                                               int M, int N, int K) {
  __shared__ __align__(16) u16 lA[128 * 32];
  __shared__ __align__(16) u16 lB[128 * 32];
  const int tid = threadIdx.x;
  const int lane = tid & 63;
  const int w = tid >> 6;
  const int wr = (w >> 1) * 64;
  const int wc = (w & 1) * 64;
  const int fr = lane & 15;
  const int fq = lane >> 4;
  const int row0 = blockIdx.x * 128;
  const int col0 = blockIdx.y * 128;

  const f32x4 z4 = {0.f, 0.f, 0.f, 0.f};
  f32x4 acc[4][4];
#pragma unroll
  for (int m = 0; m < 4; ++m)
#pragma unroll
    for (int n = 0; n < 4; ++n) acc[m][n] = z4;

  const int sr = tid >> 2;
  const int sc = (tid & 3) * 8;

  for (int k0 = 0; k0 < K; k0 += 32) {
    __syncthreads();
#pragma unroll
    for (int rep = 0; rep < 2; ++rep) {
      const int row = rep * 64 + sr;
      const int ldsbase = (rep * 256 + w * 64) * 8;
      gload16(lA + ldsbase, A + (size_t)(row0 + row) * K + (k0 + sc));
      gload16(lB + ldsbase, B + (size_t)(col0 + row) * K + (k0 + sc));
    }
    __syncthreads();

    bf16x8 af[4], bfr[4];
#pragma unroll
    for (int m = 0; m < 4; ++m)
      af[m] = *reinterpret_cast<const bf16x8*>(lA + (wr + m * 16 + fr) * 32 + fq * 8);
#pragma unroll
    for (int n = 0; n < 4; ++n)
      bfr[n] = *reinterpret_cast<const bf16x8*>(lB + (wc + n * 16 + fr) * 32 + fq * 8);
#pragma unroll
    for (int m = 0; m < 4; ++m)
#pragma unroll
      for (int n = 0; n < 4; ++n)
        acc[m][n] = __builtin_amdgcn_mfma_f32_16x16x32_bf16(af[m], bfr[n], acc[m][n], 0, 0, 0);
  }

#pragma unroll
  for (int m = 0; m < 4; ++m) {
    const int grow0 = row0 + wr + m * 16 + fq * 4;
#pragma unroll
    for (int n = 0; n < 4; ++n) {
      const int gcol = col0 + wc + n * 16 + fr;
#pragma unroll
      for (int j = 0; j < 4; ++j) {
        const size_t off = (size_t)(grow0 + j) * N + gcol;
        if (OUT_BF16) ((u16*)Cv)[off] = f2bf(acc[m][n][j]);
        else          ((float*)Cv)[off] = acc[m][n][j];
      }
    }
  }
}

// ---------------------------------------------------------------- 3D RoPE on q,k
__global__ __launch_bounds__(256) void rope_kernel(u16* __restrict__ qkv,
                                                   const float* __restrict__ Rs) {
  const int bid = blockIdx.x;        // [0, 8192)
  const int qk = bid & 1;
  const int bt = bid >> 1;
  const int t = bt & 2047;
  const int tid = threadIdx.x;

  __shared__ __align__(16) u16 buf[1536];
  __shared__ __align__(16) float rbuf[288];

  u16* g = qkv + (size_t)bt * 4608 + qk * 1536;
  if (tid < 192)
    *reinterpret_cast<uint4*>(buf + tid * 8) = *reinterpret_cast<const uint4*>(g + tid * 8);
  if (tid < 72)
    *reinterpret_cast<float4*>(rbuf + tid * 4) =
        *reinterpret_cast<const float4*>(Rs + (size_t)t * 288 + tid * 4);
  __syncthreads();

#pragma unroll
  for (int rep = 0; rep < 2; ++rep) {
    const int ft = rep * 256 + tid;
    const int base = (ft >> 5) * 96 + (ft & 31) * 3;
    const float* R = rbuf + (ft & 31) * 9;
    const float x0 = bf2f(buf[base]), x1 = bf2f(buf[base + 1]), x2 = bf2f(buf[base + 2]);
    const float y0 = R[0] * x0 + R[1] * x1 + R[2] * x2;
    const float y1 = R[3] * x0 + R[4] * x1 + R[5] * x2;
    const float y2 = R[6] * x0 + R[7] * x1 + R[8] * x2;
    buf[base] = f2bf(y0); buf[base + 1] = f2bf(y1); buf[base + 2] = f2bf(y2);
  }
  __syncthreads();
  if (tid < 192)
    *reinterpret_cast<uint4*>(g + tid * 8) = *reinterpret_cast<const uint4*>(buf + tid * 8);
}

// ---------------------------------------------------------------- KV fragment prep
// Builds, per (bh, kvtile of 64): fragment-ordered images (768 chunks of 16B each).
// K chunk (m*3+kb)*64+l  -> K[m*16+(l&15)][kb*32+(l>>4)*8 + e] * SC   (e=0..7 contig)
// V chunk (n2*2+c)*64+l, elem e -> V[(c*2+(e>>2))*16+(l>>4)*4+(e&3)][n2*16+(l&15)]
// (V e-interleave chosen so attention's P fragments come straight from registers.)
__global__ __launch_bounds__(256) void kvprep(const u16* __restrict__ qkv,
                                              u16* __restrict__ Kf,
                                              u16* __restrict__ Vf) {
  const int kt = blockIdx.x, bh = blockIdx.y;
  const int b = bh >> 4, h = bh & 15;
  const int tid = threadIdx.x, lane = tid & 63, w = tid >> 6;
  const float SC = 0.14724574f;  // (1/sqrt(96)) * log2(e)
  __shared__ __align__(16) u16 vlds[64 * 96];

  // stage V tile rows linear [64][96]
#pragma unroll
  for (int r = 0; r < 3; ++r) {
    const int idx = r * 256 + tid;
    const int kv = idx / 12, c8 = (idx % 12) * 8;
    gload16(vlds + (r * 256 + w * 64) * 8,
            qkv + (size_t)(b * 2048 + kt * 64 + kv) * 4608 + 3072 + h * 96 + c8);
  }

  const size_t obase = ((size_t)bh * 32 + kt) * 6144;
  // K chunks straight through registers (16B contiguous on both sides), scaled
#pragma unroll
  for (int r = 0; r < 3; ++r) {
    const int chunk = r * 256 + tid;
    const int sub = chunk >> 6, l = chunk & 63;
    const int m = sub / 3, kb = sub % 3;
    const int fr = l & 15, fq = l >> 4;
    uint4 v = *reinterpret_cast<const uint4*>(
        qkv + (size_t)(b * 2048 + kt * 64 + m * 16 + fr) * 4608 + 1536 + h * 96 + kb * 32 + fq * 8);
    u16* p = reinterpret_cast<u16*>(&v);
#pragma unroll
    for (int e = 0; e < 8; ++e) p[e] = f2bf(bf2f(p[e]) * SC);
    *reinterpret_cast<uint4*>(Kf + obase + (size_t)chunk * 8) = v;
  }
  __syncthreads();
  // V chunks from LDS with the e-interleave
#pragma unroll
  for (int r = 0; r < 3; ++r) {
    const int chunk = r * 256 + tid;
    const int sub = chunk >> 6, l = chunk & 63;
    const int n2 = sub >> 1, c = sub & 1;
    const int fr = l & 15, fq = l >> 4;
    const int d = n2 * 16 + fr;
    u16 out[8];
#pragma unroll
    for (int e = 0; e < 8; ++e) {
      const int kl = (c * 2 + (e >> 2)) * 16 + fq * 4 + (e & 3);
      out[e] = vlds[kl * 96 + d];
    }
    *reinterpret_cast<uint4*>(Vf + obase + (size_t)chunk * 8) =
        *reinterpret_cast<uint4*>(out);
  }
}

// ---------------------------------------------------------------- flash attention
// Block = 128 Q-rows, 4 waves x 32 rows. KV tiles of 64. 2-phase double buffer.
// Swapped QK^T (A=K): lane (fr,fq) holds S[q=nq*16+fr][k=m*16+fq*4+j] -> row-local.
__global__ __launch_bounds__(256, 2) void attn_fwd(const u16* __restrict__ qkvb,
                                                   const u16* __restrict__ Kf,
                                                   const u16* __restrict__ Vf,
                                                   u16* __restrict__ y) {
  const int bh = blockIdx.x;
  const int qt = 15 - (int)blockIdx.y;   // LPT: heavy blocks dispatched first
  const int b = bh >> 4, h = bh & 15;
  const int tid = threadIdx.x, lane = tid & 63, w = tid >> 6;
  const int fr = lane & 15, fq = lane >> 4;
  const int q0 = qt * 128;
  const int qw = q0 + w * 32;            // wave's first q row

  __shared__ __align__(16) u16 kbl[2][6144];
  __shared__ __align__(16) u16 vbl[2][6144];

  // Q fragments (unscaled; K carries scale*log2e)
  bf16x8 qf[2][3];
#pragma unroll
  for (int nq = 0; nq < 2; ++nq)
#pragma unroll
    for (int kb = 0; kb < 3; ++kb)
      qf[nq][kb] = *reinterpret_cast<const bf16x8*>(
          qkvb + (size_t)(b * 2048 + qw + nq * 16 + fr) * 4608 + h * 96 + kb * 32 + fq * 8);

  const f32x4 z4 = {0.f, 0.f, 0.f, 0.f};
  f32x4 oacc[2][6];
#pragma unroll
  for (int mq = 0; mq < 2; ++mq)
#pragma unroll
    for (int n2 = 0; n2 < 6; ++n2) oacc[mq][n2] = z4;
  float mrow[2] = {-1e30f, -1e30f}, ssum[2] = {0.f, 0.f};

  const int nt = 2 * qt + 2;
  const size_t tb = (size_t)bh * 32 * 6144;

#define STAGE(buf, kt_)                                                         \
  do {                                                                          \
    const size_t sb = tb + (size_t)(kt_)*6144;                                  \
    _Pragma("unroll") for (int r = 0; r < 3; ++r) {                             \
      gload16(kbl[buf] + (r * 256 + w * 64) * 8, Kf + sb + (r * 256 + w * 64 + lane) * 8); \
      gload16(vbl[buf] + (r * 256 + w * 64) * 8, Vf + sb + (r * 256 + w * 64 + lane) * 8); \
    }                                                                           \
  } while (0)

  STAGE(0, 0);
  for (int kt = 0; kt < nt; ++kt) {
    __syncthreads();                     // stage(kt) landed; compute(kt-1) done
    if (kt + 1 < nt) STAGE((kt + 1) & 1, kt + 1);
    const u16* kc = kbl[kt & 1];
    const u16* vc = vbl[kt & 1];
    const int k0 = kt * 64;

    if (k0 <= qw + 31) {                 // wave has unmasked work (wave-uniform)
      // ---- S^T = K Q : lane holds S[q=nq*16+fr][k=m*16+fq*4+j] (log2 domain)
      f32x4 sacc[4][2];
#pragma unroll
      for (int m = 0; m < 4; ++m)
#pragma unroll
        for (int nq = 0; nq < 2; ++nq) sacc[m][nq] = z4;
#pragma unroll
      for (int kb = 0; kb < 3; ++kb)
#pragma unroll
        for (int m = 0; m < 4; ++m) {
          const bf16x8 kfrag = *reinterpret_cast<const bf16x8*>(kc + ((m * 3 + kb) * 64 + lane) * 8);
#pragma unroll
          for (int nq = 0; nq < 2; ++nq)
            sacc[m][nq] = __builtin_amdgcn_mfma_f32_16x16x32_bf16(kfrag, qf[nq][kb], sacc[m][nq], 0, 0, 0);
        }
      // ---- causal mask
      if (k0 + 63 > qw) {
#pragma unroll
        for (int m = 0; m < 4; ++m) {
          const int kpos = k0 + m * 16 + fq * 4;
#pragma unroll
          for (int nq = 0; nq < 2; ++nq) {
            const int qpos = qw + nq * 16 + fr;
#pragma unroll
            for (int j = 0; j < 4; ++j)
              if (kpos + j > qpos) sacc[m][nq][j] = -1e30f;
          }
        }
      }
      // ---- online softmax (exp2 domain), per nq
      float al[2];
#pragma unroll
      for (int nq = 0; nq < 2; ++nq) {
        float mx = sacc[0][nq][0];
#pragma unroll
        for (int m = 0; m < 4; ++m)
#pragma unroll
          for (int j = 0; j < 4; ++j) mx = fmaxf(mx, sacc[m][nq][j]);
        mx = fmaxf(mx, __shfl_xor(mx, 16));
        mx = fmaxf(mx, __shfl_xor(mx, 32));
        const float mn = fmaxf(mrow[nq], mx);
        al[nq] = exp2f_fast(mrow[nq] - mn);
        mrow[nq] = mn;
        float s = 0.f;
#pragma unroll
        for (int m = 0; m < 4; ++m) {
          f32x4 p;
#pragma unroll
          for (int j = 0; j < 4; ++j) p[j] = exp2f_fast(sacc[m][nq][j] - mn);
          sacc[m][nq] = p;               // reuse as P
          s += (p[0] + p[1]) + (p[2] + p[3]);
        }
        s += __shfl_xor(s, 16);
        s += __shfl_xor(s, 32);
        ssum[nq] = ssum[nq] * al[nq] + s;
      }
      // ---- rescale O (al broadcast: q-row fq*4+j lives at lane fr=fq*4+j)
      float alb[2][4];
#pragma unroll
      for (int mq = 0; mq < 2; ++mq)
#pragma unroll
        for (int j = 0; j < 4; ++j) alb[mq][j] = __shfl(al[mq], fq * 4 + j);
#pragma unroll
      for (int mq = 0; mq < 2; ++mq)
#pragma unroll
        for (int n2 = 0; n2 < 6; ++n2) {
          f32x4 t = oacc[mq][n2];
          t[0] *= alb[mq][0]; t[1] *= alb[mq][1]; t[2] *= alb[mq][2]; t[3] *= alb[mq][3];
          oacc[mq][n2] = t;
        }
      // ---- pack P straight from registers (k-permutation matches Vf layout)
      union PB { u32 u[4]; bf16x8 v; };
      PB pa[2][2];
#pragma unroll
      for (int c = 0; c < 2; ++c)
#pragma unroll
        for (int mq = 0; mq < 2; ++mq) {
          pa[c][mq].u[0] = cvtpk(sacc[2 * c][mq][0], sacc[2 * c][mq][1]);
          pa[c][mq].u[1] = cvtpk(sacc[2 * c][mq][2], sacc[2 * c][mq][3]);
          pa[c][mq].u[2] = cvtpk(sacc[2 * c + 1][mq][0], sacc[2 * c + 1][mq][1]);
          pa[c][mq].u[3] = cvtpk(sacc[2 * c + 1][mq][2], sacc[2 * c + 1][mq][3]);
        }
      // ---- O += P V
#pragma unroll
      for (int c = 0; c < 2; ++c)
#pragma unroll
        for (int n2 = 0; n2 < 6; ++n2) {
          const bf16x8 vfrag = *reinterpret_cast<const bf16x8*>(vc + ((n2 * 2 + c) * 64 + lane) * 8);
#pragma unroll
          for (int mq = 0; mq < 2; ++mq)
            oacc[mq][n2] = __builtin_amdgcn_mfma_f32_16x16x32_bf16(pa[c][mq].v, vfrag, oacc[mq][n2], 0, 0, 0);
        }
    }
  }
#undef STAGE

  // ---- epilogue
  float inv[2][4];
#pragma unroll
  for (int mq = 0; mq < 2; ++mq)
#pragma unroll
    for (int j = 0; j < 4; ++j)
      inv[mq][j] = __builtin_amdgcn_rcpf(__shfl(ssum[mq], fq * 4 + j));
#pragma unroll
  for (int mq = 0; mq < 2; ++mq)
#pragma unroll
    for (int n2 = 0; n2 < 6; ++n2)
#pragma unroll
      for (int j = 0; j < 4; ++j) {
        const size_t off =
            (size_t)(b * 2048 + qw + mq * 16 + fq * 4 + j) * 1536 + h * 96 + n2 * 16 + fr;
        y[off] = f2bf(oacc[mq][n2][j] * inv[mq][j]);
      }
}

// ---------------------------------------------------------------- launch
extern "C" void kernel_launch(void* const* d_in, const int* in_sizes, int n_in,
                              void* d_out, int out_size, void* d_ws, size_t ws_size,
                              hipStream_t stream) {
  (void)in_sizes; (void)n_in; (void)out_size; (void)ws_size;
  const float* x     = (const float*)d_in[0];
  const float* w_qkv = (const float*)d_in[1];
  const float* w_o   = (const float*)d_in[2];
  const float* Rs    = (const float*)d_in[3];
  float* out = (float*)d_out;

  // ws layout (u16 elems). Kf/Vf alias xb/wqkvb (dead after gemm1). Total 81.8 MB.
  u16* xb    = (u16*)d_ws;            // 6291456
  u16* wqkvb = xb + 6291456;          // 7077888
  u16* wob   = xb + 13369344;         // 2359296
  u16* qkvb  = xb + 15728640;         // 18874368
  u16* yb    = xb + 34603008;         // 6291456
  u16* Kf    = xb;                    // 6291456 (32 bh x 32 kt x 6144)
  u16* Vf    = xb + 6291456;          // 6291456

  cvt_bf16<<<1572864 / 256, 256, 0, stream>>>(x, xb, 1572864);
  cvt_bf16<<<1769472 / 256, 256, 0, stream>>>(w_qkv, wqkvb, 1769472);
  cvt_bf16<<<589824 / 256, 256, 0, stream>>>(w_o, wob, 589824);

  gemm_bt<1><<<dim3(32, 36), 256, 0, stream>>>(xb, wqkvb, (void*)qkvb, 4096, 4608, 1536);
  rope_kernel<<<8192, 256, 0, stream>>>(qkvb, Rs);
  kvprep<<<dim3(32, 32), 256, 0, stream>>>(qkvb, Kf, Vf);
  attn_fwd<<<dim3(32, 16), 256, 0, stream>>>(qkvb, Kf, Vf, yb);
  gemm_bt<0><<<dim3(32, 12), 256, 0, stream>>>(yb, wob, (void*)out, 4096, 1536, 1536);
}